// Round 9
// baseline (196.485 us; speedup 1.0000x reference)
//
#include <hip/hip_runtime.h>

typedef unsigned short u16;
typedef __attribute__((ext_vector_type(8))) short s16x8;           // 8 bf16 = 4 VGPRs (MFMA A/B frag)
typedef __attribute__((ext_vector_type(8))) unsigned short u16x8;  // memory staging
typedef __attribute__((ext_vector_type(4))) unsigned short u16x4;  // 8B packed P-write
typedef __attribute__((ext_vector_type(4))) float f32x4;           // MFMA C/D frag

__device__ __forceinline__ u16 f2bf(float f) {
  unsigned int u = __float_as_uint(f);
  u += 0x7fffu + ((u >> 16) & 1u);   // RNE
  return (u16)(u >> 16);
}

// async global->LDS, 16B per lane (m97 pattern: dest must be uniform base + lane*16)
__device__ __forceinline__ void gload_lds16(const u16* g, u16* l) {
  __builtin_amdgcn_global_load_lds((__attribute__((address_space(1))) void*)(u16*)g,
                                   (__attribute__((address_space(3))) void*)l, 16, 0, 0);
}

// ---------------------------------------------------------------- fused prep:
// blocks [0,2048): cvt x->bf16; [2048,5120): transpose wqkv; [5120,6144): transpose wout
__global__ void __launch_bounds__(256) prep_kernel(const float* __restrict__ x,
                                                   u16* __restrict__ xbf,
                                                   const float* __restrict__ wqkv,
                                                   u16* __restrict__ wqkvT,
                                                   const float* __restrict__ wout,
                                                   u16* __restrict__ woutT) {
  __shared__ float tile[32][33];
  const int b = blockIdx.x, tid = threadIdx.x;
  if (b < 2048) {
    int i = (b * 256 + tid) * 8;
    float4 a = *(const float4*)(x + i);
    float4 c = *(const float4*)(x + i + 4);
    u16x8 o;
    o[0] = f2bf(a.x); o[1] = f2bf(a.y); o[2] = f2bf(a.z); o[3] = f2bf(a.w);
    o[4] = f2bf(c.x); o[5] = f2bf(c.y); o[6] = f2bf(c.z); o[7] = f2bf(c.w);
    *(u16x8*)(xbf + i) = o;
    return;
  }
  const float* in; u16* out; int K = 1024, N, bx, by;
  if (b < 5120) { in = wqkv; out = wqkvT; N = 3072; bx = (b - 2048) % 96; by = (b - 2048) / 96; }
  else          { in = wout; out = woutT; N = 1024; bx = (b - 5120) % 32; by = (b - 5120) / 32; }
  int n0 = bx * 32, k0 = by * 32;
  int r = tid >> 5, c = tid & 31;
#pragma unroll
  for (int i = 0; i < 4; ++i)
    tile[r + i * 8][c] = in[(size_t)(k0 + r + i * 8) * N + n0 + c];
  __syncthreads();
#pragma unroll
  for (int i = 0; i < 4; ++i)
    out[(size_t)(n0 + r + i * 8) * K + k0 + c] = f2bf(tile[c][r + i * 8]);
}

// ------------------------------------- QKV GEMM v3: x[4096,1024] @ wqkvT[3072,1024]^T
// 128x96 tiles, grid 1024 = 4 blocks/CU. Two changes vs R8 (which measured 49us,
// MfmaUtil 20.5% -> ~900cyc exposed latency/iter):
//  (1) REGISTER-PREFETCH staging (attn-proven): loads for k+1 issue before compute of k,
//      so the vmcnt wait lands after a full compute phase. Replaces global_load_lds
//      (whose barrier-drain serialized full memory latency into every iteration).
//  (2) XCD swizzle: xcd = lid%8 owns 4 n-tiles (0.75MB of W, L2-resident) x all m.
__global__ void __launch_bounds__(256, 4) gemm_qkv_kernel(const u16* __restrict__ xbf,
                                                          const u16* __restrict__ wT,
                                                          const float* __restrict__ bias,
                                                          u16* __restrict__ qb,
                                                          u16* __restrict__ kb,
                                                          u16* __restrict__ vtb) {
  __shared__ u16 As[128 * 32];   // 8KB
  __shared__ u16 Bs[96 * 32];    // 6KB
  f32x4 acc[4][3];
#pragma unroll
  for (int i = 0; i < 4; ++i)
#pragma unroll
    for (int j = 0; j < 3; ++j) { f32x4 z = {0.f, 0.f, 0.f, 0.f}; acc[i][j] = z; }
  const int lid = blockIdx.y * 32 + blockIdx.x;
  const int xcd = lid & 7, idx = lid >> 3;        // assume xcd = linear_id % 8
  const int m0 = (idx & 31) * 128;
  const int n0 = ((xcd << 2) | (idx >> 5)) * 96;  // 4 consecutive n-tiles per XCD
  const int K = 1024;

  const int tid = threadIdx.x;
  const int lane = tid & 63, wave = tid >> 6;
  const int quad = lane >> 4, l16 = lane & 15;
  const int wm = (wave & 1) << 6, wn = (wave >> 1) * 48;
  // A staging: 8KB = 2 x 16B per thread
  const int ob0 = wave * 2048 + lane * 16;
  const int ob1 = ob0 + 1024;
  const int r0 = ob0 >> 6, c0 = (ob0 & 63) >> 1;
  const int r1 = ob1 >> 6, c1 = (ob1 & 63) >> 1;
  // B staging: 6KB = 16B per thread + 16B for tid<128
  const int obB0 = tid * 16;
  const int obB1 = 4096 + tid * 16;
  const int rB0 = obB0 >> 6, cB0 = (obB0 & 63) >> 1;
  const int rB1 = obB1 >> 6, cB1 = (obB1 & 63) >> 1;

  u16x8 av0, av1, bv0, bv1;
  av0 = *(const u16x8*)&xbf[(size_t)(m0 + r0) * K + c0];
  av1 = *(const u16x8*)&xbf[(size_t)(m0 + r1) * K + c1];
  bv0 = *(const u16x8*)&wT[(size_t)(n0 + rB0) * K + cB0];
  if (tid < 128) bv1 = *(const u16x8*)&wT[(size_t)(n0 + rB1) * K + cB1];

  for (int k0 = 0; k0 < K; k0 += 32) {
    __syncthreads();  // previous iteration's frag reads complete
    *(u16x8*)&As[ob0 >> 1] = av0;
    *(u16x8*)&As[ob1 >> 1] = av1;
    *(u16x8*)&Bs[obB0 >> 1] = bv0;
    if (tid < 128) *(u16x8*)&Bs[obB1 >> 1] = bv1;
    __syncthreads();  // lgkm-only drain: LDS visible
    if (k0 + 32 < K) {  // prefetch next tile; vmcnt wait lands after compute below
      av0 = *(const u16x8*)&xbf[(size_t)(m0 + r0) * K + k0 + 32 + c0];
      av1 = *(const u16x8*)&xbf[(size_t)(m0 + r1) * K + k0 + 32 + c1];
      bv0 = *(const u16x8*)&wT[(size_t)(n0 + rB0) * K + k0 + 32 + cB0];
      if (tid < 128) bv1 = *(const u16x8*)&wT[(size_t)(n0 + rB1) * K + k0 + 32 + cB1];
    }
    s16x8 a[4], b[3];
#pragma unroll
    for (int i = 0; i < 4; ++i)
      a[i] = *(const s16x8*)&As[(wm + i * 16 + l16) * 32 + quad * 8];
#pragma unroll
    for (int j = 0; j < 3; ++j)
      b[j] = *(const s16x8*)&Bs[(wn + j * 16 + l16) * 32 + quad * 8];
#pragma unroll
    for (int i = 0; i < 4; ++i)
#pragma unroll
      for (int j = 0; j < 3; ++j)
        acc[i][j] = __builtin_amdgcn_mfma_f32_16x16x32_bf16(a[i], b[j], acc[i][j], 0, 0, 0);
  }

  // epilogue: per-element section (96 does not divide 1024; only 2/32 n-tiles diverge)
#pragma unroll
  for (int i = 0; i < 4; ++i)
#pragma unroll
    for (int j = 0; j < 3; ++j) {
      const int gm = m0 + wm + i * 16 + quad * 4;
      const int gn = n0 + wn + j * 16 + l16;
      const float bv = bias[gn];
      const int sec = gn >> 10;
      const int c = gn & 1023, h = c >> 6, d = c & 63;
#pragma unroll
      for (int r = 0; r < 4; ++r) {
        const int row = gm + r;
        const int bb = row >> 11, t = row & 2047;
        if (sec == 0)      qb[((size_t)(bb * 16 + h) * 2048 + t) * 64 + d] = f2bf((acc[i][j][r] + bv) * 0.125f);
        else if (sec == 1) kb[((size_t)(bb * 16 + h) * 2048 + t) * 64 + d] = f2bf(acc[i][j][r] + bv);
        else               vtb[((size_t)(bb * 16 + h) * 64 + d) * 2048 + t] = f2bf(acc[i][j][r] + bv);
      }
    }
}

// ------------------------------------- out GEMM: y[4096,1024] @ woutT[1024,1024]^T -> f32
// 64x128 tiles, grid (64,8)=512 blocks -> 2 blocks/CU. BK=32 single-buffer (R4/R6 measured best).
__global__ void __launch_bounds__(256) gemm_out_kernel(const u16* __restrict__ yb,
                                                       const u16* __restrict__ wT,
                                                       const float* __restrict__ bias,
                                                       float* __restrict__ out) {
  __shared__ u16 As[64 * 32], Bs[128 * 32];
  f32x4 acc[2][4];
#pragma unroll
  for (int i = 0; i < 2; ++i)
#pragma unroll
    for (int j = 0; j < 4; ++j) { f32x4 z = {0.f, 0.f, 0.f, 0.f}; acc[i][j] = z; }
  const int m0 = blockIdx.x * 64, n0 = blockIdx.y * 128;
  const int K = 1024;

  const int tid = threadIdx.x;
  const int lane = tid & 63, wave = tid >> 6;
  const int quad = lane >> 4, l16 = lane & 15;
  const int wm = (wave & 1) << 5, wn = (wave >> 1) << 6;
  const int oa = tid * 16;
  const int ra = oa >> 6, ca = (oa & 63) >> 1;
  const int ob0 = wave * 2048 + lane * 16;
  const int ob1 = ob0 + 1024;
  const int rb0 = ob0 >> 6, cb0 = (ob0 & 63) >> 1;
  const int rb1 = ob1 >> 6, cb1 = (ob1 & 63) >> 1;

  for (int k0 = 0; k0 < K; k0 += 32) {
    __syncthreads();
    gload_lds16(&yb[(size_t)(m0 + ra) * K + k0 + ca],  &As[oa >> 1]);
    gload_lds16(&wT[(size_t)(n0 + rb0) * K + k0 + cb0], &Bs[ob0 >> 1]);
    gload_lds16(&wT[(size_t)(n0 + rb1) * K + k0 + cb1], &Bs[ob1 >> 1]);
    __syncthreads();
    s16x8 a[2], b[4];
#pragma unroll
    for (int i = 0; i < 2; ++i)
      a[i] = *(const s16x8*)&As[(wm + i * 16 + l16) * 32 + quad * 8];
#pragma unroll
    for (int j = 0; j < 4; ++j)
      b[j] = *(const s16x8*)&Bs[(wn + j * 16 + l16) * 32 + quad * 8];
#pragma unroll
    for (int i = 0; i < 2; ++i)
#pragma unroll
      for (int j = 0; j < 4; ++j)
        acc[i][j] = __builtin_amdgcn_mfma_f32_16x16x32_bf16(a[i], b[j], acc[i][j], 0, 0, 0);
  }

#pragma unroll
  for (int i = 0; i < 2; ++i)
#pragma unroll
    for (int j = 0; j < 4; ++j) {
      const int gm = m0 + wm + i * 16 + quad * 4;
      const int gn = n0 + wn + j * 16 + l16;
      const float bv = bias[gn];
#pragma unroll
      for (int r = 0; r < 4; ++r)
        out[(size_t)(gm + r) * 1024 + gn] = acc[i][j][r] + bv;
    }
}

// ---------------------------------------------------------------- flash attention v3
// (measured 47.5/48.2 us rounds 3/5; core untouched. NEW: XCD swizzle — each XCD owns
// 4 complete bh (2MB K/V < 4MB L2) so K/V re-reads across a head's 16 blocks hit L2.)
__global__ void __launch_bounds__(256) attn_kernel(const u16* __restrict__ qb,
                                                   const u16* __restrict__ kb,
                                                   const u16* __restrict__ vtb,
                                                   u16* __restrict__ yb) {
  const int KSTR = 72, VSTR = 136;
  __shared__ u16 Ks[128 * 72];              // K super-tile [krow][d] (also Q staging)
  __shared__ u16 VTs[64 * 136];             // V^T super-tile [d][kcol 0..127]
  __shared__ u16 Ps[4 * 16 * 136];          // per-wave P [qrow_local][kcol 0..127]

  const int lid = blockIdx.y * 16 + blockIdx.x;
  const int xcd = lid & 7, idx = lid >> 3;        // assume xcd = linear_id % 8
  const int bh = (xcd << 2) | (idx >> 4);         // 4 bh per XCD
  const int p  = idx & 15;                        // 0..15
  const int bb = bh >> 4, h = bh & 15;
  const u16* Q  = qb  + (size_t)bh * (2048 * 64);
  const u16* Km = kb  + (size_t)bh * (2048 * 64);
  const u16* VT = vtb + (size_t)bh * (64 * 2048);

  const int tid = threadIdx.x;
  const int wave = tid >> 6, lane = tid & 63;
  const int quad = lane >> 4, l16 = lane & 15;
  const float NINF = -__builtin_inff();
  const int Kr = tid >> 3, Kc = (tid & 7) * 8;    // K staging: rows +32/iter
  const int Vr = tid >> 4, Vc = (tid & 15) * 8;   // V^T staging: rows +16/iter
  u16* Pw = Ps + wave * (16 * 136);

  for (int pass = 0; pass < 2; ++pass) {
    const int qt = pass ? (31 - p) : p;
    const int nkt = (qt >> 1) + 1;          // 128-wide K tiles covering 0..(qt+1)*64-1
    // ---- stage Q tile (rows qt*64..+63) into Ks, pull B-frags to regs
    __syncthreads();                        // prev pass frag reads done
#pragma unroll
    for (int i = 0; i < 2; ++i) {
      int r = Kr + i * 32;
      *(u16x8*)&Ks[r * KSTR + Kc] = *(const u16x8*)&Q[(size_t)(qt * 64 + r) * 64 + Kc];
    }
    __syncthreads();
    s16x8 qf[2];
#pragma unroll
    for (int ks = 0; ks < 2; ++ks)
      qf[ks] = *(const s16x8*)&Ks[(wave * 16 + l16) * KSTR + ks * 32 + quad * 8];

    float lsum = 0.f;
    f32x4 oacc[4];
#pragma unroll
    for (int dt = 0; dt < 4; ++dt) { f32x4 z = {0.f, 0.f, 0.f, 0.f}; oacc[dt] = z; }

    u16x8 kv[4], vv[4];
#pragma unroll
    for (int i = 0; i < 4; ++i) {           // prefetch super-tile 0
      kv[i] = *(const u16x8*)&Km[(size_t)(Kr + i * 32) * 64 + Kc];
      vv[i] = *(const u16x8*)&VT[(size_t)(Vr + i * 16) * 2048 + Vc];
    }

    for (int kt = 0; kt < nkt; ++kt) {
      __syncthreads();                      // prev frag reads (incl. qf) done
#pragma unroll
      for (int i = 0; i < 4; ++i) {
        *(u16x8*)&Ks[(Kr + i * 32) * KSTR + Kc]  = kv[i];
        *(u16x8*)&VTs[(Vr + i * 16) * VSTR + Vc] = vv[i];
      }
      __syncthreads();
      if (kt + 1 < nkt) {                   // prefetch next super-tile during compute
#pragma unroll
        for (int i = 0; i < 4; ++i) {
          kv[i] = *(const u16x8*)&Km[(size_t)((kt + 1) * 128 + Kr + i * 32) * 64 + Kc];
          vv[i] = *(const u16x8*)&VT[(size_t)(Vr + i * 16) * 2048 + (kt + 1) * 128 + Vc];
        }
      }
      // ---- S^T = K * Q^T : lane(quad,l16) reg[hh][mt][r] = S[qrow=l16][kcol=hh*64+mt*16+quad*4+r]
      f32x4 st[2][4];
#pragma unroll
      for (int hh = 0; hh < 2; ++hh)
#pragma unroll
        for (int mt = 0; mt < 4; ++mt) {
          f32x4 z = {0.f, 0.f, 0.f, 0.f};
          s16x8 kf0 = *(const s16x8*)&Ks[(hh * 64 + mt * 16 + l16) * KSTR + quad * 8];
          s16x8 kf1 = *(const s16x8*)&Ks[(hh * 64 + mt * 16 + l16) * KSTR + 32 + quad * 8];
          z = __builtin_amdgcn_mfma_f32_16x16x32_bf16(kf0, qf[0], z, 0, 0, 0);
          st[hh][mt] = __builtin_amdgcn_mfma_f32_16x16x32_bf16(kf1, qf[1], z, 0, 0, 0);
        }
      // ---- causal mask (last super-tile only; scale folded into Q)
      if (kt == nkt - 1) {
        const int qrow = qt * 64 + wave * 16 + l16;
#pragma unroll
        for (int hh = 0; hh < 2; ++hh)
#pragma unroll
          for (int mt = 0; mt < 4; ++mt)
#pragma unroll
            for (int r = 0; r < 4; ++r) {
              int kcol = kt * 128 + hh * 64 + mt * 16 + quad * 4 + r;
              if (kcol > qrow) st[hh][mt][r] = NINF;
            }
      }
      // ---- P = exp(s), per-lane l partial, pack bf16 (round-half-up), write P
#pragma unroll
      for (int hh = 0; hh < 2; ++hh)
#pragma unroll
        for (int mt = 0; mt < 4; ++mt) {
          u16x4 pw;
#pragma unroll
          for (int r = 0; r < 4; ++r) {
            float e = __expf(st[hh][mt][r]);   // exp(-inf)=0 for masked
            lsum += e;
            pw[r] = (u16)((__float_as_uint(e) + 0x8000u) >> 16);
          }
          *(u16x4*)&Pw[l16 * VSTR + hh * 64 + mt * 16 + quad * 4] = pw;
        }
      // ---- O += P * V  (same-wave LDS round-trip, in-order DS)
#pragma unroll
      for (int kq = 0; kq < 4; ++kq) {
        s16x8 pf = *(const s16x8*)&Pw[l16 * VSTR + kq * 32 + quad * 8];
#pragma unroll
        for (int dt = 0; dt < 4; ++dt) {
          s16x8 vf = *(const s16x8*)&VTs[(dt * 16 + l16) * VSTR + kq * 32 + quad * 8];
          oacc[dt] = __builtin_amdgcn_mfma_f32_16x16x32_bf16(pf, vf, oacc[dt], 0, 0, 0);
        }
      }
    }  // kt

    // ---- single l reduction per pass, then epilogue: y[b,t,h,d] = O / l
    float l = lsum;
    l += __shfl_xor(l, 16, 64);
    l += __shfl_xor(l, 32, 64);
    float rinv[4];
#pragma unroll
    for (int r = 0; r < 4; ++r) rinv[r] = 1.0f / __shfl(l, quad * 4 + r, 64);
#pragma unroll
    for (int dt = 0; dt < 4; ++dt) {
      int d = dt * 16 + l16;
#pragma unroll
      for (int r = 0; r < 4; ++r) {
        int t = qt * 64 + wave * 16 + quad * 4 + r;
        yb[(((size_t)bb * 2048 + t) * 16 + h) * 64 + d] = f2bf(oacc[dt][r] * rinv[r]);
      }
    }
  }  // pass
}

// ---------------------------------------------------------------- launch
extern "C" void kernel_launch(void* const* d_in, const int* in_sizes, int n_in,
                              void* d_out, int out_size, void* d_ws, size_t ws_size,
                              hipStream_t stream) {
  (void)in_sizes; (void)n_in; (void)out_size; (void)ws_size;
  const float* x    = (const float*)d_in[0];  // [2,2048,1024]
  const float* wqkv = (const float*)d_in[1];  // [1024,3072]
  const float* bqkv = (const float*)d_in[2];  // [3072]
  const float* wout = (const float*)d_in[3];  // [1024,1024]
  const float* bout = (const float*)d_in[4];  // [1024]
  float* out = (float*)d_out;                 // [2,2048,1024] f32

  char* ws = (char*)d_ws;  // 48 MB used
  u16* xbf   = (u16*)(ws);                                  //  8 MB [4096][1024]
  u16* wqkvT = (u16*)(ws + (size_t)8  * 1024 * 1024);       //  6 MB [3072][1024]
  u16* woutT = (u16*)(ws + (size_t)14 * 1024 * 1024);       //  2 MB [1024][1024]
  u16* qb    = (u16*)(ws + (size_t)16 * 1024 * 1024);       //  8 MB [B,H,T,D] (pre-scaled)
  u16* kb    = (u16*)(ws + (size_t)24 * 1024 * 1024);       //  8 MB [B,H,T,D]
  u16* vtb   = (u16*)(ws + (size_t)32 * 1024 * 1024);       //  8 MB [B,H,D,T]
  u16* yb    = (u16*)(ws + (size_t)40 * 1024 * 1024);       //  8 MB [B,T,H,D]

  prep_kernel<<<6144, 256, 0, stream>>>(x, xbf, wqkv, wqkvT, wout, woutT);
  gemm_qkv_kernel<<<dim3(32, 32), 256, 0, stream>>>(xbf, wqkvT, bqkv, qb, kb, vtb);
  attn_kernel<<<dim3(16, 32), 256, 0, stream>>>(qb, kb, vtb, yb);
  gemm_out_kernel<<<dim3(64, 8), 256, 0, stream>>>(yb, woutT, bout, out);
}

// Round 10
// 179.493 us; speedup vs baseline: 1.0947x; 1.0947x over previous
//
#include <hip/hip_runtime.h>

typedef unsigned short u16;
typedef __attribute__((ext_vector_type(8))) short s16x8;           // 8 bf16 = 4 VGPRs (MFMA A/B frag)
typedef __attribute__((ext_vector_type(8))) unsigned short u16x8;  // memory staging
typedef __attribute__((ext_vector_type(4))) unsigned short u16x4;  // 8B packed P-write
typedef __attribute__((ext_vector_type(4))) float f32x4;           // MFMA C/D frag

__device__ __forceinline__ u16 f2bf(float f) {
  unsigned int u = __float_as_uint(f);
  u += 0x7fffu + ((u >> 16) & 1u);   // RNE
  return (u16)(u >> 16);
}

// async global->LDS, 16B per lane (m97 pattern: dest must be uniform base + lane*16)
__device__ __forceinline__ void gload_lds16(const u16* g, u16* l) {
  __builtin_amdgcn_global_load_lds((__attribute__((address_space(1))) void*)(u16*)g,
                                   (__attribute__((address_space(3))) void*)l, 16, 0, 0);
}

// ---------------------------------------------------------------- fused prep:
// blocks [0,2048): cvt x->bf16; [2048,5120): transpose wqkv; [5120,6144): transpose wout
__global__ void __launch_bounds__(256) prep_kernel(const float* __restrict__ x,
                                                   u16* __restrict__ xbf,
                                                   const float* __restrict__ wqkv,
                                                   u16* __restrict__ wqkvT,
                                                   const float* __restrict__ wout,
                                                   u16* __restrict__ woutT) {
  __shared__ float tile[32][33];
  const int b = blockIdx.x, tid = threadIdx.x;
  if (b < 2048) {
    int i = (b * 256 + tid) * 8;
    float4 a = *(const float4*)(x + i);
    float4 c = *(const float4*)(x + i + 4);
    u16x8 o;
    o[0] = f2bf(a.x); o[1] = f2bf(a.y); o[2] = f2bf(a.z); o[3] = f2bf(a.w);
    o[4] = f2bf(c.x); o[5] = f2bf(c.y); o[6] = f2bf(c.z); o[7] = f2bf(c.w);
    *(u16x8*)(xbf + i) = o;
    return;
  }
  const float* in; u16* out; int K = 1024, N, bx, by;
  if (b < 5120) { in = wqkv; out = wqkvT; N = 3072; bx = (b - 2048) % 96; by = (b - 2048) / 96; }
  else          { in = wout; out = woutT; N = 1024; bx = (b - 5120) % 32; by = (b - 5120) / 32; }
  int n0 = bx * 32, k0 = by * 32;
  int r = tid >> 5, c = tid & 31;
#pragma unroll
  for (int i = 0; i < 4; ++i)
    tile[r + i * 8][c] = in[(size_t)(k0 + r + i * 8) * N + n0 + c];
  __syncthreads();
#pragma unroll
  for (int i = 0; i < 4; ++i)
    out[(size_t)(n0 + r + i * 8) * K + k0 + c] = f2bf(tile[c][r + i * 8]);
}

// ---------------------------------------------------------------- GEMM core (m97 style)
// C[128,128] += A[128,K] * BT[128,K]^T. LDS tiles 128x32 bf16, UNPADDED (64B rows) so
// global_load_lds lane addresses are contiguous. 256 thr = 4 waves, wave = 64x64 out.
// MEASURED VERDICTS: dbuf (R5), BK=64 (R7), reg-prefetch+swizzle (R9) all REGRESS;
// this exact single-buffer form is the structure's floor (~46-49us at K=1024).
__device__ __forceinline__ void gemm_core(const u16* __restrict__ A,
                                          const u16* __restrict__ BT, int K,
                                          int m0, int n0, u16* As, u16* Bs,
                                          f32x4 acc[4][4]) {
  const int tid = threadIdx.x;
  const int lane = tid & 63, wave = tid >> 6;
  const int quad = lane >> 4, l16 = lane & 15;
  const int wm = (wave & 1) << 6, wn = (wave >> 1) << 6;
  const int ob0 = wave * 2048 + lane * 16;
  const int ob1 = ob0 + 1024;
  const int r0 = ob0 >> 6, c0 = (ob0 & 63) >> 1;
  const int r1 = ob1 >> 6, c1 = (ob1 & 63) >> 1;

  for (int k0 = 0; k0 < K; k0 += 32) {
    __syncthreads();  // previous iteration's frag reads complete
    gload_lds16(&A [(size_t)(m0 + r0) * K + k0 + c0], &As[ob0 >> 1]);
    gload_lds16(&A [(size_t)(m0 + r1) * K + k0 + c1], &As[ob1 >> 1]);
    gload_lds16(&BT[(size_t)(n0 + r0) * K + k0 + c0], &Bs[ob0 >> 1]);
    gload_lds16(&BT[(size_t)(n0 + r1) * K + k0 + c1], &Bs[ob1 >> 1]);
    __syncthreads();  // drains vmcnt -> LDS visible
    s16x8 a[4], b[4];
#pragma unroll
    for (int i = 0; i < 4; ++i)
      a[i] = *(const s16x8*)&As[(wm + i * 16 + l16) * 32 + quad * 8];
#pragma unroll
    for (int j = 0; j < 4; ++j)
      b[j] = *(const s16x8*)&Bs[(wn + j * 16 + l16) * 32 + quad * 8];
#pragma unroll
    for (int i = 0; i < 4; ++i)
#pragma unroll
      for (int j = 0; j < 4; ++j)
        acc[i][j] = __builtin_amdgcn_mfma_f32_16x16x32_bf16(a[i], b[j], acc[i][j], 0, 0, 0);
  }
}

// ------------------------------------- QKV GEMM: x[4096,1024] @ wqkvT[3072,1024]^T
// (R4/R6 exact form: 128x128, grid (32,24), natural L2 locality — R9's XCD swizzle
// raised FETCH 28.8->43.4MB and regressed; do not re-add.)
__global__ void __launch_bounds__(256) gemm_qkv_kernel(const u16* __restrict__ xbf,
                                                       const u16* __restrict__ wT,
                                                       const float* __restrict__ bias,
                                                       u16* __restrict__ qb,
                                                       u16* __restrict__ kb,
                                                       u16* __restrict__ vtb) {
  __shared__ u16 As[128 * 32], Bs[128 * 32];
  f32x4 acc[4][4];
#pragma unroll
  for (int i = 0; i < 4; ++i)
#pragma unroll
    for (int j = 0; j < 4; ++j) { f32x4 z = {0.f, 0.f, 0.f, 0.f}; acc[i][j] = z; }
  const int m0 = blockIdx.x * 128, n0 = blockIdx.y * 128;
  gemm_core(xbf, wT, 1024, m0, n0, As, Bs, acc);

  const int tid = threadIdx.x;
  const int lane = tid & 63, wave = tid >> 6;
  const int quad = lane >> 4, l16 = lane & 15;
  const int wm = (wave & 1) << 6, wn = (wave >> 1) << 6;
  const int sec = n0 >> 10;  // 0=q 1=k 2=v (uniform per block)
#pragma unroll
  for (int i = 0; i < 4; ++i)
#pragma unroll
    for (int j = 0; j < 4; ++j) {
      const int gm = m0 + wm + i * 16 + quad * 4;
      const int gn = n0 + wn + j * 16 + l16;
      const float bv = bias[gn];
      const int c = gn & 1023, h = c >> 6, d = c & 63;
#pragma unroll
      for (int r = 0; r < 4; ++r) {
        const int row = gm + r;
        const int bb = row >> 11, t = row & 2047;
        if (sec == 0)      qb[((size_t)(bb * 16 + h) * 2048 + t) * 64 + d] = f2bf((acc[i][j][r] + bv) * 0.125f);
        else if (sec == 1) kb[((size_t)(bb * 16 + h) * 2048 + t) * 64 + d] = f2bf(acc[i][j][r] + bv);
        else               vtb[((size_t)(bb * 16 + h) * 64 + d) * 2048 + t] = f2bf(acc[i][j][r] + bv);
      }
    }
}

// ------------------------------------- out GEMM: y[4096,1024] @ woutT[1024,1024]^T -> f32
// 64x128 tiles, grid (64,8)=512 blocks -> 2 blocks/CU. (R4/R6 measured best)
__global__ void __launch_bounds__(256) gemm_out_kernel(const u16* __restrict__ yb,
                                                       const u16* __restrict__ wT,
                                                       const float* __restrict__ bias,
                                                       float* __restrict__ out) {
  __shared__ u16 As[64 * 32], Bs[128 * 32];
  f32x4 acc[2][4];
#pragma unroll
  for (int i = 0; i < 2; ++i)
#pragma unroll
    for (int j = 0; j < 4; ++j) { f32x4 z = {0.f, 0.f, 0.f, 0.f}; acc[i][j] = z; }
  const int m0 = blockIdx.x * 64, n0 = blockIdx.y * 128;
  const int K = 1024;

  const int tid = threadIdx.x;
  const int lane = tid & 63, wave = tid >> 6;
  const int quad = lane >> 4, l16 = lane & 15;
  const int wm = (wave & 1) << 5, wn = (wave >> 1) << 6;
  const int oa = tid * 16;
  const int ra = oa >> 6, ca = (oa & 63) >> 1;
  const int ob0 = wave * 2048 + lane * 16;
  const int ob1 = ob0 + 1024;
  const int rb0 = ob0 >> 6, cb0 = (ob0 & 63) >> 1;
  const int rb1 = ob1 >> 6, cb1 = (ob1 & 63) >> 1;

  for (int k0 = 0; k0 < K; k0 += 32) {
    __syncthreads();
    gload_lds16(&yb[(size_t)(m0 + ra) * K + k0 + ca],  &As[oa >> 1]);
    gload_lds16(&wT[(size_t)(n0 + rb0) * K + k0 + cb0], &Bs[ob0 >> 1]);
    gload_lds16(&wT[(size_t)(n0 + rb1) * K + k0 + cb1], &Bs[ob1 >> 1]);
    __syncthreads();
    s16x8 a[2], b[4];
#pragma unroll
    for (int i = 0; i < 2; ++i)
      a[i] = *(const s16x8*)&As[(wm + i * 16 + l16) * 32 + quad * 8];
#pragma unroll
    for (int j = 0; j < 4; ++j)
      b[j] = *(const s16x8*)&Bs[(wn + j * 16 + l16) * 32 + quad * 8];
#pragma unroll
    for (int i = 0; i < 2; ++i)
#pragma unroll
      for (int j = 0; j < 4; ++j)
        acc[i][j] = __builtin_amdgcn_mfma_f32_16x16x32_bf16(a[i], b[j], acc[i][j], 0, 0, 0);
  }

#pragma unroll
  for (int i = 0; i < 2; ++i)
#pragma unroll
    for (int j = 0; j < 4; ++j) {
      const int gm = m0 + wm + i * 16 + quad * 4;
      const int gn = n0 + wn + j * 16 + l16;
      const float bv = bias[gn];
#pragma unroll
      for (int r = 0; r < 4; ++r)
        out[(size_t)(gm + r) * 1024 + gn] = acc[i][j][r] + bv;
    }
}

// ---------------------------------------------------------------- flash attention v3 + XCD swizzle
// Core thrice-measured (47.5/48.2/~48). XCD swizzle (R9): each XCD owns 4 complete bh
// (2MB K/V < 4MB L2) — R9 rest-delta suggests ~-3us; kept. Paired q-tiles (p, 31-p):
// every block exactly 17 128-wide super-iterations, zero tail.
__global__ void __launch_bounds__(256) attn_kernel(const u16* __restrict__ qb,
                                                   const u16* __restrict__ kb,
                                                   const u16* __restrict__ vtb,
                                                   u16* __restrict__ yb) {
  const int KSTR = 72, VSTR = 136;
  __shared__ u16 Ks[128 * 72];              // K super-tile [krow][d] (also Q staging)
  __shared__ u16 VTs[64 * 136];             // V^T super-tile [d][kcol 0..127]
  __shared__ u16 Ps[4 * 16 * 136];          // per-wave P [qrow_local][kcol 0..127]

  const int lid = blockIdx.y * 16 + blockIdx.x;
  const int xcd = lid & 7, idx = lid >> 3;        // assume xcd = linear_id % 8
  const int bh = (xcd << 2) | (idx >> 4);         // 4 bh per XCD
  const int p  = idx & 15;                        // 0..15
  const int bb = bh >> 4, h = bh & 15;
  const u16* Q  = qb  + (size_t)bh * (2048 * 64);
  const u16* Km = kb  + (size_t)bh * (2048 * 64);
  const u16* VT = vtb + (size_t)bh * (64 * 2048);

  const int tid = threadIdx.x;
  const int wave = tid >> 6, lane = tid & 63;
  const int quad = lane >> 4, l16 = lane & 15;
  const float NINF = -__builtin_inff();
  const int Kr = tid >> 3, Kc = (tid & 7) * 8;    // K staging: rows +32/iter
  const int Vr = tid >> 4, Vc = (tid & 15) * 8;   // V^T staging: rows +16/iter
  u16* Pw = Ps + wave * (16 * 136);

  for (int pass = 0; pass < 2; ++pass) {
    const int qt = pass ? (31 - p) : p;
    const int nkt = (qt >> 1) + 1;          // 128-wide K tiles covering 0..(qt+1)*64-1
    // ---- stage Q tile (rows qt*64..+63) into Ks, pull B-frags to regs
    __syncthreads();                        // prev pass frag reads done
#pragma unroll
    for (int i = 0; i < 2; ++i) {
      int r = Kr + i * 32;
      *(u16x8*)&Ks[r * KSTR + Kc] = *(const u16x8*)&Q[(size_t)(qt * 64 + r) * 64 + Kc];
    }
    __syncthreads();
    s16x8 qf[2];
#pragma unroll
    for (int ks = 0; ks < 2; ++ks)
      qf[ks] = *(const s16x8*)&Ks[(wave * 16 + l16) * KSTR + ks * 32 + quad * 8];

    float lsum = 0.f;
    f32x4 oacc[4];
#pragma unroll
    for (int dt = 0; dt < 4; ++dt) { f32x4 z = {0.f, 0.f, 0.f, 0.f}; oacc[dt] = z; }

    u16x8 kv[4], vv[4];
#pragma unroll
    for (int i = 0; i < 4; ++i) {           // prefetch super-tile 0
      kv[i] = *(const u16x8*)&Km[(size_t)(Kr + i * 32) * 64 + Kc];
      vv[i] = *(const u16x8*)&VT[(size_t)(Vr + i * 16) * 2048 + Vc];
    }

    for (int kt = 0; kt < nkt; ++kt) {
      __syncthreads();                      // prev frag reads (incl. qf) done
#pragma unroll
      for (int i = 0; i < 4; ++i) {
        *(u16x8*)&Ks[(Kr + i * 32) * KSTR + Kc]  = kv[i];
        *(u16x8*)&VTs[(Vr + i * 16) * VSTR + Vc] = vv[i];
      }
      __syncthreads();
      if (kt + 1 < nkt) {                   // prefetch next super-tile during compute
#pragma unroll
        for (int i = 0; i < 4; ++i) {
          kv[i] = *(const u16x8*)&Km[(size_t)((kt + 1) * 128 + Kr + i * 32) * 64 + Kc];
          vv[i] = *(const u16x8*)&VT[(size_t)(Vr + i * 16) * 2048 + (kt + 1) * 128 + Vc];
        }
      }
      // ---- S^T = K * Q^T : lane(quad,l16) reg[hh][mt][r] = S[qrow=l16][kcol=hh*64+mt*16+quad*4+r]
      f32x4 st[2][4];
#pragma unroll
      for (int hh = 0; hh < 2; ++hh)
#pragma unroll
        for (int mt = 0; mt < 4; ++mt) {
          f32x4 z = {0.f, 0.f, 0.f, 0.f};
          s16x8 kf0 = *(const s16x8*)&Ks[(hh * 64 + mt * 16 + l16) * KSTR + quad * 8];
          s16x8 kf1 = *(const s16x8*)&Ks[(hh * 64 + mt * 16 + l16) * KSTR + 32 + quad * 8];
          z = __builtin_amdgcn_mfma_f32_16x16x32_bf16(kf0, qf[0], z, 0, 0, 0);
          st[hh][mt] = __builtin_amdgcn_mfma_f32_16x16x32_bf16(kf1, qf[1], z, 0, 0, 0);
        }
      // ---- causal mask (last super-tile only; scale folded into Q)
      if (kt == nkt - 1) {
        const int qrow = qt * 64 + wave * 16 + l16;
#pragma unroll
        for (int hh = 0; hh < 2; ++hh)
#pragma unroll
          for (int mt = 0; mt < 4; ++mt)
#pragma unroll
            for (int r = 0; r < 4; ++r) {
              int kcol = kt * 128 + hh * 64 + mt * 16 + quad * 4 + r;
              if (kcol > qrow) st[hh][mt][r] = NINF;
            }
      }
      // ---- P = exp(s), per-lane l partial, pack bf16 (round-half-up), write P
#pragma unroll
      for (int hh = 0; hh < 2; ++hh)
#pragma unroll
        for (int mt = 0; mt < 4; ++mt) {
          u16x4 pw;
#pragma unroll
          for (int r = 0; r < 4; ++r) {
            float e = __expf(st[hh][mt][r]);   // exp(-inf)=0 for masked
            lsum += e;
            pw[r] = (u16)((__float_as_uint(e) + 0x8000u) >> 16);
          }
          *(u16x4*)&Pw[l16 * VSTR + hh * 64 + mt * 16 + quad * 4] = pw;
        }
      // ---- O += P * V  (same-wave LDS round-trip, in-order DS)
#pragma unroll
      for (int kq = 0; kq < 4; ++kq) {
        s16x8 pf = *(const s16x8*)&Pw[l16 * VSTR + kq * 32 + quad * 8];
#pragma unroll
        for (int dt = 0; dt < 4; ++dt) {
          s16x8 vf = *(const s16x8*)&VTs[(dt * 16 + l16) * VSTR + kq * 32 + quad * 8];
          oacc[dt] = __builtin_amdgcn_mfma_f32_16x16x32_bf16(pf, vf, oacc[dt], 0, 0, 0);
        }
      }
    }  // kt

    // ---- single l reduction per pass, then epilogue: y[b,t,h,d] = O / l
    float l = lsum;
    l += __shfl_xor(l, 16, 64);
    l += __shfl_xor(l, 32, 64);
    float rinv[4];
#pragma unroll
    for (int r = 0; r < 4; ++r) rinv[r] = 1.0f / __shfl(l, quad * 4 + r, 64);
#pragma unroll
    for (int dt = 0; dt < 4; ++dt) {
      int d = dt * 16 + l16;
#pragma unroll
      for (int r = 0; r < 4; ++r) {
        int t = qt * 64 + wave * 16 + quad * 4 + r;
        yb[(((size_t)bb * 2048 + t) * 16 + h) * 64 + d] = f2bf(oacc[dt][r] * rinv[r]);
      }
    }
  }  // pass
}

// ---------------------------------------------------------------- launch
extern "C" void kernel_launch(void* const* d_in, const int* in_sizes, int n_in,
                              void* d_out, int out_size, void* d_ws, size_t ws_size,
                              hipStream_t stream) {
  (void)in_sizes; (void)n_in; (void)out_size; (void)ws_size;
  const float* x    = (const float*)d_in[0];  // [2,2048,1024]
  const float* wqkv = (const float*)d_in[1];  // [1024,3072]
  const float* bqkv = (const float*)d_in[2];  // [3072]
  const float* wout = (const float*)d_in[3];  // [1024,1024]
  const float* bout = (const float*)d_in[4];  // [1024]
  float* out = (float*)d_out;                 // [2,2048,1024] f32

  char* ws = (char*)d_ws;  // 48 MB used
  u16* xbf   = (u16*)(ws);                                  //  8 MB [4096][1024]
  u16* wqkvT = (u16*)(ws + (size_t)8  * 1024 * 1024);       //  6 MB [3072][1024]
  u16* woutT = (u16*)(ws + (size_t)14 * 1024 * 1024);       //  2 MB [1024][1024]
  u16* qb    = (u16*)(ws + (size_t)16 * 1024 * 1024);       //  8 MB [B,H,T,D] (pre-scaled)
  u16* kb    = (u16*)(ws + (size_t)24 * 1024 * 1024);       //  8 MB [B,H,T,D]
  u16* vtb   = (u16*)(ws + (size_t)32 * 1024 * 1024);       //  8 MB [B,H,D,T]
  u16* yb    = (u16*)(ws + (size_t)40 * 1024 * 1024);       //  8 MB [B,T,H,D]

  prep_kernel<<<6144, 256, 0, stream>>>(x, xbf, wqkv, wqkvT, wout, woutT);
  gemm_qkv_kernel<<<dim3(32, 24), 256, 0, stream>>>(xbf, wqkvT, bqkv, qb, kb, vtb);
  attn_kernel<<<dim3(16, 32), 256, 0, stream>>>(qb, kb, vtb, yb);
  gemm_out_kernel<<<dim3(64, 8), 256, 0, stream>>>(yb, woutT, bout, out);
}